// Round 12
// baseline (75.382 us; speedup 1.0000x reference)
//
#include <hip/hip_runtime.h>
#include <math.h>

#define VOCAB 100000
#define DIM 128
#define BATCH 4096
#define CTX 20
#define NEGS 10
#define NTARG (CTX + CTX * NEGS)   // 220
#define NB 32                      // row buckets: 3125 rows
#define ROWS_PER_B 3125
#define CAP 20                     // recs per (bucket,b) cell; lambda=6.875
#define SPILL_MAX 8192
#define SPILL_BLOCKS 8

// d_ws layout (bytes) — tiered
#define OFF_COUNTS   0u            // u8[NB*BATCH] = 131072
#define OFF_SPILLCNT 131072u       // u32 (+pad to 131200)
#define OFF_SPILL    131200u       // u32[SPILL_MAX] = 32768
#define OFF_RECORDS  163968u       // u16[NB*BATCH*CAP] = 5242880
#define OFF_IVEC     5406848u      // f32[BATCH*DIM] = 2097152
#define WS_NEEDED_MID 7504000u
#define OFF_WOS16    7504000u      // bf16[VOCAB*DIM] = 25600000
#define WS_NEEDED_BF16 33104000u
#define CONV_BLOCKS 6250           // 12.8M floats / 8 per thread / 256

__device__ __forceinline__ float log_sigmoid_fast(float x) {
    float a = fabsf(x);
    return fminf(x, 0.0f) - __logf(1.0f + __expf(-a));
}

__device__ __forceinline__ unsigned short f2bf_rtne(float f) {
    unsigned u = __float_as_uint(f);
    return (unsigned short)((u + 0x7fffu + ((u >> 16) & 1u)) >> 16);
}

// ---- Kernel P: fused prep ----
// blocks [0,256):      scatter (16 ex/block, 16 thr/ex, LDS-atomic counters)
// blocks [256,768):    ivec[b] = W_i[i_words[b]] f32 stage
// blocks [768,768+CONV_BLOCKS): W_os f32 -> bf16 (only launched in bf16 path)
__global__ __launch_bounds__(256) void prep_kernel(
    const int* __restrict__ i_words, const int* __restrict__ o_words,
    const int* __restrict__ n_words, const float4* __restrict__ W_i4,
    const float4* __restrict__ W_os4, float4* __restrict__ ivec4,
    unsigned short* __restrict__ wos16, unsigned short* __restrict__ records,
    unsigned char* __restrict__ counts, unsigned* __restrict__ spillcnt,
    unsigned* __restrict__ spill)
{
    if (blockIdx.x >= 768) {                     // W_os -> bf16, 8 floats/thread
        unsigned tid2 = (blockIdx.x - 768) * 256 + threadIdx.x;  // < 1.6M
        float4 a = W_os4[tid2 * 2];
        float4 b = W_os4[tid2 * 2 + 1];
        ushort4 lo, hi;
        lo.x = f2bf_rtne(a.x); lo.y = f2bf_rtne(a.y);
        lo.z = f2bf_rtne(a.z); lo.w = f2bf_rtne(a.w);
        hi.x = f2bf_rtne(b.x); hi.y = f2bf_rtne(b.y);
        hi.z = f2bf_rtne(b.z); hi.w = f2bf_rtne(b.w);
        ((ushort4*)wos16)[tid2 * 2]     = lo;
        ((ushort4*)wos16)[tid2 * 2 + 1] = hi;
        return;
    }
    if (blockIdx.x >= 256) {
        int tid = (blockIdx.x - 256) * 256 + threadIdx.x;   // 131072 = BATCH*32
        int b = tid >> 5, q = tid & 31;
        ivec4[tid] = W_i4[i_words[b] * 32 + q];
        return;
    }
    const int exl = threadIdx.x >> 4;          // example within block
    const int t   = threadIdx.x & 15;
    const int b   = blockIdx.x * 16 + exl;

    __shared__ unsigned lcnt[NB * 16];         // 2 KB
    for (int k = threadIdx.x; k < NB * 16; k += 256) lcnt[k] = 0;
    __syncthreads();

    for (int j = t; j < NTARG; j += 16) {
        int idx; unsigned negbit;
        if (j < CTX) { idx = o_words[j * BATCH + b];                negbit = 0u; }
        else         { idx = n_words[b * (CTX * NEGS) + (j - CTX)]; negbit = 0x1000u; }
        unsigned bucket = (unsigned)idx / ROWS_PER_B;
        unsigned rl     = (unsigned)idx - bucket * ROWS_PER_B;
        unsigned slot = atomicAdd(&lcnt[bucket * 16 + (unsigned)exl], 1u);
        if (slot < CAP) {
            records[((bucket << 12) + (unsigned)b) * CAP + slot] = (unsigned short)(rl | negbit);
        } else {
            unsigned s = atomicAdd(spillcnt, 1u);
            if (s < SPILL_MAX) spill[s] = ((unsigned)idx << 13) | ((unsigned)b << 1) | (negbit ? 1u : 0u);
        }
    }
    __syncthreads();
    for (int k = threadIdx.x; k < NB * 16; k += 256) {
        unsigned c = lcnt[k];
        unsigned bucket = (unsigned)k >> 4, e2 = (unsigned)k & 15u;
        counts[(bucket << 12) + (unsigned)blockIdx.x * 16 + e2] = (unsigned char)(c < CAP ? c : CAP);
    }
}

// ---- Kernel C (bf16 rows): one 16-lane group per (bucket,b) cell ----
__global__ __launch_bounds__(256) void bucket_loss_bf16_kernel(
    const unsigned short* __restrict__ wos16, const float* __restrict__ W_os,
    const float* __restrict__ ivec,
    const unsigned short* __restrict__ records, const unsigned char* __restrict__ counts,
    const unsigned* __restrict__ spillcnt, const unsigned* __restrict__ spill,
    float* __restrict__ out)
{
    const int t    = threadIdx.x & 15;
    const int grp  = threadIdx.x >> 4;
    const int lane = threadIdx.x & 63;
    const int wave = threadIdx.x >> 6;
    const unsigned tb16 = (unsigned)t << 4;        // byte offset in 256B bf16 row
    const unsigned* rec32 = (const unsigned*)records;

    float acc = 0.0f;
    const int lid = blockIdx.x;

    if (lid < 2048) {
        const int xcd = lid & 7;
        const int s   = lid >> 3;                  // 0..255
        const unsigned bcell = (unsigned)(s * 16 + grp);

        const char* vp = (const char*)ivec + ((bcell << 9) + ((unsigned)t << 5));
        const float4 va = *(const float4*)vp;      // ivec f32, once per group
        const float4 vb = *(const float4*)(vp + 16);

        for (int bk = 0; bk < NB / 8; ++bk) {
            const unsigned bucket = (unsigned)(xcd * (NB / 8) + bk);
            const unsigned cell   = (bucket << 12) + bcell;
            const unsigned cnt    = counts[cell];
            unsigned w = 0;
            if (t < 10) w = rec32[cell * 10u + (unsigned)t];

            for (unsigned base = 0; base < cnt; base += 8) {
                unsigned recs[8]; uint4 rw[8];
                #pragma unroll
                for (int i = 0; i < 8; ++i) {      // broadcast recs + 1 load/pair
                    unsigned ji = base + (unsigned)i;
                    int src = (grp << 4) + (int)(ji >> 1);
                    unsigned wv  = __shfl(w, src, 64);
                    unsigned rec = (i & 1) ? (wv >> 16) : (wv & 0xffffu);
                    recs[i] = rec;
                    unsigned rowg = (ji < cnt) ? (bucket * ROWS_PER_B + (rec & 0xfffu)) : 0u;
                    rw[i] = *(const uint4*)((const char*)wos16 + ((rowg << 8) + tb16));
                }
                #pragma unroll
                for (int i = 0; i < 8; ++i) {      // bf16 extract + dot + loss
                    unsigned ji = base + (unsigned)i;
                    float pd;
                    pd = __uint_as_float(rw[i].x << 16) * va.x;
                    pd = fmaf(__uint_as_float(rw[i].x & 0xffff0000u), va.y, pd);
                    pd = fmaf(__uint_as_float(rw[i].y << 16),         va.z, pd);
                    pd = fmaf(__uint_as_float(rw[i].y & 0xffff0000u), va.w, pd);
                    pd = fmaf(__uint_as_float(rw[i].z << 16),         vb.x, pd);
                    pd = fmaf(__uint_as_float(rw[i].z & 0xffff0000u), vb.y, pd);
                    pd = fmaf(__uint_as_float(rw[i].w << 16),         vb.z, pd);
                    pd = fmaf(__uint_as_float(rw[i].w & 0xffff0000u), vb.w, pd);
                    pd += __shfl_xor(pd, 1);
                    pd += __shfl_xor(pd, 2);
                    pd += __shfl_xor(pd, 4);
                    pd += __shfl_xor(pd, 8);
                    float term = (recs[i] & 0x1000u)
                               ? (1.0f / NEGS) * log_sigmoid_fast(-pd)
                               : (1.0f / CTX)  * log_sigmoid_fast(pd);
                    if (t == 0 && ji < cnt) acc += term;
                }
            }
        }
    } else {
        // spill groups: f32 originals (exactness; expected ~0-2 entries)
        int sg = (lid - 2048) * 16 + grp;
        unsigned ns = *spillcnt; if (ns > SPILL_MAX) ns = SPILL_MAX;
        for (unsigned s = sg; s < ns; s += 16 * SPILL_BLOCKS) {
            unsigned e = spill[s];
            unsigned row = e >> 13, bb = (e >> 1) & 4095u;
            const char* rp = (const char*)W_os + ((row << 9) + ((unsigned)t << 5));
            float4 r0 = *(const float4*)rp, r1 = *(const float4*)(rp + 16);
            const char* vp2 = (const char*)ivec + ((bb << 9) + ((unsigned)t << 5));
            float4 v0 = *(const float4*)vp2, v1 = *(const float4*)(vp2 + 16);
            float pd = r0.x*v0.x + r0.y*v0.y + r0.z*v0.z + r0.w*v0.w
                     + r1.x*v1.x + r1.y*v1.y + r1.z*v1.z + r1.w*v1.w;
            pd += __shfl_xor(pd, 1);
            pd += __shfl_xor(pd, 2);
            pd += __shfl_xor(pd, 4);
            pd += __shfl_xor(pd, 8);
            float term = (e & 1u) ? (1.0f / NEGS) * log_sigmoid_fast(-pd)
                                  : (1.0f / CTX)  * log_sigmoid_fast(pd);
            if (t == 0) acc += term;
        }
    }

    acc += __shfl_xor(acc, 16);
    acc += __shfl_xor(acc, 32);
    __shared__ float wsum[4];
    if (lane == 0) wsum[wave] = acc;
    __syncthreads();
    if (threadIdx.x == 0) {
        float sum = wsum[0] + wsum[1] + wsum[2] + wsum[3];
        if (sum != 0.0f) atomicAdd(out, -sum);
    }
}

// ---- Kernel C (f32 rows, round-11 middle fallback) ----
__global__ __launch_bounds__(256) void bucket_loss_kernel(
    const float* __restrict__ W_os, const float* __restrict__ ivec,
    const unsigned short* __restrict__ records, const unsigned char* __restrict__ counts,
    const unsigned* __restrict__ spillcnt, const unsigned* __restrict__ spill,
    float* __restrict__ out)
{
    const int t    = threadIdx.x & 15;
    const int grp  = threadIdx.x >> 4;
    const int lane = threadIdx.x & 63;
    const int wave = threadIdx.x >> 6;
    const unsigned tb = (unsigned)t << 5;
    const unsigned* rec32 = (const unsigned*)records;

    float acc = 0.0f;
    const int lid = blockIdx.x;

    if (lid < 2048) {
        const int xcd = lid & 7;
        const int s   = lid >> 3;
        const unsigned bcell = (unsigned)(s * 16 + grp);

        const char* vp = (const char*)ivec + ((bcell << 9) + tb);
        const float4 v0 = *(const float4*)vp;
        const float4 v1 = *(const float4*)(vp + 16);

        for (int bk = 0; bk < NB / 8; ++bk) {
            const unsigned bucket = (unsigned)(xcd * (NB / 8) + bk);
            const unsigned cell   = (bucket << 12) + bcell;
            const unsigned cnt    = counts[cell];
            unsigned w = 0;
            if (t < 10) w = rec32[cell * 10u + (unsigned)t];

            for (unsigned base = 0; base < cnt; base += 8) {
                unsigned recs[8]; float4 r0[8], r1[8];
                #pragma unroll
                for (int i = 0; i < 8; ++i) {
                    unsigned ji = base + (unsigned)i;
                    int src = (grp << 4) + (int)(ji >> 1);
                    unsigned wv  = __shfl(w, src, 64);
                    unsigned rec = (i & 1) ? (wv >> 16) : (wv & 0xffffu);
                    recs[i] = rec;
                    unsigned rowg = (ji < cnt) ? (bucket * ROWS_PER_B + (rec & 0xfffu)) : 0u;
                    const char* rp = (const char*)W_os + ((rowg << 9) + tb);
                    r0[i] = *(const float4*)rp;
                    r1[i] = *(const float4*)(rp + 16);
                }
                #pragma unroll
                for (int i = 0; i < 8; ++i) {
                    unsigned ji = base + (unsigned)i;
                    float pd = r0[i].x*v0.x + r0[i].y*v0.y + r0[i].z*v0.z + r0[i].w*v0.w
                             + r1[i].x*v1.x + r1[i].y*v1.y + r1[i].z*v1.z + r1[i].w*v1.w;
                    pd += __shfl_xor(pd, 1);
                    pd += __shfl_xor(pd, 2);
                    pd += __shfl_xor(pd, 4);
                    pd += __shfl_xor(pd, 8);
                    float term = (recs[i] & 0x1000u)
                               ? (1.0f / NEGS) * log_sigmoid_fast(-pd)
                               : (1.0f / CTX)  * log_sigmoid_fast(pd);
                    if (t == 0 && ji < cnt) acc += term;
                }
            }
        }
    } else {
        int sg = (lid - 2048) * 16 + grp;
        unsigned ns = *spillcnt; if (ns > SPILL_MAX) ns = SPILL_MAX;
        for (unsigned s = sg; s < ns; s += 16 * SPILL_BLOCKS) {
            unsigned e = spill[s];
            unsigned row = e >> 13, bb = (e >> 1) & 4095u;
            const char* rp = (const char*)W_os + ((row << 9) + tb);
            float4 r0 = *(const float4*)rp, r1 = *(const float4*)(rp + 16);
            const char* vp2 = (const char*)ivec + ((bb << 9) + tb);
            float4 v0 = *(const float4*)vp2, v1 = *(const float4*)(vp2 + 16);
            float pd = r0.x*v0.x + r0.y*v0.y + r0.z*v0.z + r0.w*v0.w
                     + r1.x*v1.x + r1.y*v1.y + r1.z*v1.z + r1.w*v1.w;
            pd += __shfl_xor(pd, 1);
            pd += __shfl_xor(pd, 2);
            pd += __shfl_xor(pd, 4);
            pd += __shfl_xor(pd, 8);
            float term = (e & 1u) ? (1.0f / NEGS) * log_sigmoid_fast(-pd)
                                  : (1.0f / CTX)  * log_sigmoid_fast(pd);
            if (t == 0) acc += term;
        }
    }

    acc += __shfl_xor(acc, 16);
    acc += __shfl_xor(acc, 32);
    __shared__ float wsum[4];
    if (lane == 0) wsum[wave] = acc;
    __syncthreads();
    if (threadIdx.x == 0) {
        float sum = wsum[0] + wsum[1] + wsum[2] + wsum[3];
        if (sum != 0.0f) atomicAdd(out, -sum);
    }
}

// ---- Fallback (round-5 direct kernel) if ws too small ----
__global__ __launch_bounds__(256) void sgns_loss_direct(
    const int* __restrict__ i_words, const int* __restrict__ o_words,
    const int* __restrict__ n_words, const float* __restrict__ W_i,
    const float* __restrict__ W_os, float* __restrict__ out)
{
    const int lane = threadIdx.x & 63;
    const int wave = threadIdx.x >> 6;
    const int w    = blockIdx.x * 4 + wave;
    const int b    = w >> 1;
    const int h    = w & 1;
    const int sub = lane >> 4;
    const int t   = lane & 15;
    const int j_begin = h ? 112 : 0;
    const int j_end   = h ? NTARG : 112;
    float acc = 0.0f;
    const int ic = i_words[b];
    const char* ibase = (const char*)W_i + (((unsigned)ic << 9) + ((unsigned)t << 5));
    float4 i0 = *(const float4*)(ibase);
    float4 i1 = *(const float4*)(ibase + 16);
    #pragma unroll 4
    for (int j0 = j_begin; j0 < j_end; j0 += 4) {
        int jj = j0 + sub;
        int idx; float sgn, wgt;
        if (jj < CTX) { idx = o_words[jj * BATCH + b]; sgn = 1.0f; wgt = 1.0f / CTX; }
        else { idx = n_words[b * (CTX * NEGS) + (jj - CTX)]; sgn = -1.0f; wgt = 1.0f / NEGS; }
        const char* obase = (const char*)W_os + (((unsigned)idx << 9) + ((unsigned)t << 5));
        float4 o0 = *(const float4*)(obase);
        float4 o1 = *(const float4*)(obase + 16);
        float p = i0.x*o0.x + i0.y*o0.y + i0.z*o0.z + i0.w*o0.w
                + i1.x*o1.x + i1.y*o1.y + i1.z*o1.z + i1.w*o1.w;
        p += __shfl_xor(p, 1); p += __shfl_xor(p, 2);
        p += __shfl_xor(p, 4); p += __shfl_xor(p, 8);
        acc += (t == 0) ? wgt * log_sigmoid_fast(sgn * p) : 0.0f;
    }
    acc += __shfl_xor(acc, 16);
    acc += __shfl_xor(acc, 32);
    __shared__ float ws[4];
    if (lane == 0) ws[wave] = acc;
    __syncthreads();
    if (threadIdx.x == 0) atomicAdd(out, -(ws[0] + ws[1] + ws[2] + ws[3]));
}

extern "C" void kernel_launch(void* const* d_in, const int* in_sizes, int n_in,
                              void* d_out, int out_size, void* d_ws, size_t ws_size,
                              hipStream_t stream) {
    const int*   i_words = (const int*)d_in[0];
    const int*   o_words = (const int*)d_in[1];
    const int*   n_words = (const int*)d_in[2];
    const float* W_i     = (const float*)d_in[3];
    const float* W_os    = (const float*)d_in[4];
    float* out = (float*)d_out;

    hipMemsetAsync(out, 0, sizeof(float), stream);

    if (ws_size < (size_t)WS_NEEDED_MID) {
        sgns_loss_direct<<<2048, 256, 0, stream>>>(i_words, o_words, n_words, W_i, W_os, out);
        return;
    }

    char* ws = (char*)d_ws;
    unsigned char*  counts   = (unsigned char*)(ws + OFF_COUNTS);
    unsigned*       spillcnt = (unsigned*)(ws + OFF_SPILLCNT);
    unsigned*       spill    = (unsigned*)(ws + OFF_SPILL);
    unsigned short* records  = (unsigned short*)(ws + OFF_RECORDS);
    float*          ivec     = (float*)(ws + OFF_IVEC);
    unsigned short* wos16    = (unsigned short*)(ws + OFF_WOS16);

    hipMemsetAsync(spillcnt, 0, sizeof(unsigned), stream);

    if (ws_size >= (size_t)WS_NEEDED_BF16) {
        prep_kernel<<<768 + CONV_BLOCKS, 256, 0, stream>>>(
            i_words, o_words, n_words, (const float4*)W_i, (const float4*)W_os,
            (float4*)ivec, wos16, records, counts, spillcnt, spill);
        bucket_loss_bf16_kernel<<<2048 + SPILL_BLOCKS, 256, 0, stream>>>(
            wos16, W_os, ivec, records, counts, spillcnt, spill, out);
    } else {
        prep_kernel<<<768, 256, 0, stream>>>(
            i_words, o_words, n_words, (const float4*)W_i, (const float4*)W_os,
            (float4*)ivec, wos16, records, counts, spillcnt, spill);
        bucket_loss_kernel<<<2048 + SPILL_BLOCKS, 256, 0, stream>>>(
            W_os, ivec, records, counts, spillcnt, spill, out);
    }
}

// Round 13
// 72.296 us; speedup vs baseline: 1.0427x; 1.0427x over previous
//
#include <hip/hip_runtime.h>
#include <math.h>

#define VOCAB 100000
#define DIM 128
#define BATCH 4096
#define CTX 20
#define NEGS 10
#define NTARG (CTX + CTX * NEGS)   // 220
#define NB 32                      // row buckets: 3125 rows
#define ROWS_PER_B 3125
#define CAP 20                     // recs per (bucket,b) cell; lambda=6.875
#define SPILL_MAX 8192
#define SPILL_BLOCKS 8

// d_ws layout (bytes) — tiered
#define OFF_COUNTS   0u            // u8[NB*BATCH] = 131072
#define OFF_SPILLCNT 131072u       // u32 (+pad to 131200)
#define OFF_SPILL    131200u       // u32[SPILL_MAX] = 32768
#define OFF_RECORDS  163968u       // u16[NB*BATCH*CAP] = 5242880
#define OFF_IVEC     5406848u      // f32[BATCH*DIM] = 2097152
#define WS_NEEDED_MID 7504000u
#define OFF_WOS16    7504000u      // bf16[VOCAB*DIM] = 25600000
#define WS_NEEDED_BF16 33104000u
#define CONV_BLOCKS 6250           // 12.8M floats / 8 per thread / 256

#if defined(__has_builtin)
#if __has_builtin(__builtin_amdgcn_fdot2_f32_bf16)
#define USE_DOT2 1
#endif
#endif

#ifdef USE_DOT2
typedef __bf16 bf16x2_t __attribute__((ext_vector_type(2)));
__device__ __forceinline__ bf16x2_t u2bf2(unsigned u) {
    union { unsigned u; bf16x2_t v; } c; c.u = u; return c.v;
}
#endif

__device__ __forceinline__ float log_sigmoid_fast(float x) {
    float a = fabsf(x);
    return fminf(x, 0.0f) - __logf(1.0f + __expf(-a));
}

__device__ __forceinline__ unsigned short f2bf_rtne(float f) {
    unsigned u = __float_as_uint(f);
    return (unsigned short)((u + 0x7fffu + ((u >> 16) & 1u)) >> 16);
}

// ---- Kernel P: fused prep ----
// blocks [0,256):      scatter (16 ex/block, 16 thr/ex, LDS-atomic counters)
// blocks [256,768):    ivec[b] = W_i[i_words[b]] f32 stage
// blocks [768,768+CONV_BLOCKS): W_os f32 -> bf16
__global__ __launch_bounds__(256) void prep_kernel(
    const int* __restrict__ i_words, const int* __restrict__ o_words,
    const int* __restrict__ n_words, const float4* __restrict__ W_i4,
    const float4* __restrict__ W_os4, float4* __restrict__ ivec4,
    unsigned short* __restrict__ wos16, unsigned short* __restrict__ records,
    unsigned char* __restrict__ counts, unsigned* __restrict__ spillcnt,
    unsigned* __restrict__ spill)
{
    if (blockIdx.x >= 768) {                     // W_os -> bf16, 8 floats/thread
        unsigned tid2 = (blockIdx.x - 768) * 256 + threadIdx.x;  // < 1.6M
        float4 a = W_os4[tid2 * 2];
        float4 b = W_os4[tid2 * 2 + 1];
        ushort4 lo, hi;
        lo.x = f2bf_rtne(a.x); lo.y = f2bf_rtne(a.y);
        lo.z = f2bf_rtne(a.z); lo.w = f2bf_rtne(a.w);
        hi.x = f2bf_rtne(b.x); hi.y = f2bf_rtne(b.y);
        hi.z = f2bf_rtne(b.z); hi.w = f2bf_rtne(b.w);
        ((ushort4*)wos16)[tid2 * 2]     = lo;
        ((ushort4*)wos16)[tid2 * 2 + 1] = hi;
        return;
    }
    if (blockIdx.x >= 256) {
        int tid = (blockIdx.x - 256) * 256 + threadIdx.x;   // 131072 = BATCH*32
        int b = tid >> 5, q = tid & 31;
        ivec4[tid] = W_i4[i_words[b] * 32 + q];
        return;
    }
    const int exl = threadIdx.x >> 4;          // example within block
    const int t   = threadIdx.x & 15;
    const int b   = blockIdx.x * 16 + exl;

    __shared__ unsigned lcnt[NB * 16];         // 2 KB
    for (int k = threadIdx.x; k < NB * 16; k += 256) lcnt[k] = 0;
    __syncthreads();

    for (int j = t; j < NTARG; j += 16) {
        int idx; unsigned negbit;
        if (j < CTX) { idx = o_words[j * BATCH + b];                negbit = 0u; }
        else         { idx = n_words[b * (CTX * NEGS) + (j - CTX)]; negbit = 0x1000u; }
        unsigned bucket = (unsigned)idx / ROWS_PER_B;
        unsigned rl     = (unsigned)idx - bucket * ROWS_PER_B;
        unsigned slot = atomicAdd(&lcnt[bucket * 16 + (unsigned)exl], 1u);
        if (slot < CAP) {
            records[((bucket << 12) + (unsigned)b) * CAP + slot] = (unsigned short)(rl | negbit);
        } else {
            unsigned s = atomicAdd(spillcnt, 1u);
            if (s < SPILL_MAX) spill[s] = ((unsigned)idx << 13) | ((unsigned)b << 1) | (negbit ? 1u : 0u);
        }
    }
    __syncthreads();
    for (int k = threadIdx.x; k < NB * 16; k += 256) {
        unsigned c = lcnt[k];
        unsigned bucket = (unsigned)k >> 4, e2 = (unsigned)k & 15u;
        counts[(bucket << 12) + (unsigned)blockIdx.x * 16 + e2] = (unsigned char)(c < CAP ? c : CAP);
    }
}

// ---- Kernel C (bf16 rows + packed dot2): one 16-lane group per (bucket,b) cell ----
__global__ __launch_bounds__(256) void bucket_loss_bf16_kernel(
    const unsigned short* __restrict__ wos16, const float* __restrict__ W_os,
    const float* __restrict__ ivec,
    const unsigned short* __restrict__ records, const unsigned char* __restrict__ counts,
    const unsigned* __restrict__ spillcnt, const unsigned* __restrict__ spill,
    float* __restrict__ out)
{
    const int t    = threadIdx.x & 15;
    const int grp  = threadIdx.x >> 4;
    const int lane = threadIdx.x & 63;
    const int wave = threadIdx.x >> 6;
    const unsigned tb16 = (unsigned)t << 4;        // byte offset in 256B bf16 row
    const unsigned* rec32 = (const unsigned*)records;

    float acc = 0.0f;
    const int lid = blockIdx.x;

    if (lid < 2048) {
        const int xcd = lid & 7;
        const int s   = lid >> 3;                  // 0..255
        const unsigned bcell = (unsigned)(s * 16 + grp);

        const char* vp = (const char*)ivec + ((bcell << 9) + ((unsigned)t << 5));
        const float4 va = *(const float4*)vp;      // ivec f32, once per group
        const float4 vb = *(const float4*)(vp + 16);

#ifdef USE_DOT2
        // pack ivec slice to bf16x2 once per group (amortized over ~27 pairs)
        const unsigned iv0 = ((unsigned)f2bf_rtne(va.y) << 16) | f2bf_rtne(va.x);
        const unsigned iv1 = ((unsigned)f2bf_rtne(va.w) << 16) | f2bf_rtne(va.z);
        const unsigned iv2 = ((unsigned)f2bf_rtne(vb.y) << 16) | f2bf_rtne(vb.x);
        const unsigned iv3 = ((unsigned)f2bf_rtne(vb.w) << 16) | f2bf_rtne(vb.z);
        const bf16x2_t ivv0 = u2bf2(iv0), ivv1 = u2bf2(iv1);
        const bf16x2_t ivv2 = u2bf2(iv2), ivv3 = u2bf2(iv3);
#endif

        for (int bk = 0; bk < NB / 8; ++bk) {
            const unsigned bucket = (unsigned)(xcd * (NB / 8) + bk);
            const unsigned cell   = (bucket << 12) + bcell;
            const unsigned cnt    = counts[cell];
            unsigned w = 0;
            if (t < 10) w = rec32[cell * 10u + (unsigned)t];

            for (unsigned base = 0; base < cnt; base += 8) {
                unsigned recs[8]; uint4 rw[8];
                #pragma unroll
                for (int i = 0; i < 8; ++i) {      // broadcast recs + 1 load/pair
                    unsigned ji = base + (unsigned)i;
                    int src = (grp << 4) + (int)(ji >> 1);
                    unsigned wv  = __shfl(w, src, 64);
                    unsigned rec = (i & 1) ? (wv >> 16) : (wv & 0xffffu);
                    recs[i] = rec;
                    unsigned rowg = (ji < cnt) ? (bucket * ROWS_PER_B + (rec & 0xfffu)) : 0u;
                    rw[i] = *(const uint4*)((const char*)wos16 + ((rowg << 8) + tb16));
                }
                #pragma unroll
                for (int i = 0; i < 8; ++i) {      // dot + reduce + loss
                    unsigned ji = base + (unsigned)i;
                    float pd;
#ifdef USE_DOT2
                    pd = __builtin_amdgcn_fdot2_f32_bf16(u2bf2(rw[i].x), ivv0, 0.0f, false);
                    pd = __builtin_amdgcn_fdot2_f32_bf16(u2bf2(rw[i].y), ivv1, pd,   false);
                    pd = __builtin_amdgcn_fdot2_f32_bf16(u2bf2(rw[i].z), ivv2, pd,   false);
                    pd = __builtin_amdgcn_fdot2_f32_bf16(u2bf2(rw[i].w), ivv3, pd,   false);
#else
                    pd = __uint_as_float(rw[i].x << 16) * va.x;
                    pd = fmaf(__uint_as_float(rw[i].x & 0xffff0000u), va.y, pd);
                    pd = fmaf(__uint_as_float(rw[i].y << 16),         va.z, pd);
                    pd = fmaf(__uint_as_float(rw[i].y & 0xffff0000u), va.w, pd);
                    pd = fmaf(__uint_as_float(rw[i].z << 16),         vb.x, pd);
                    pd = fmaf(__uint_as_float(rw[i].z & 0xffff0000u), vb.y, pd);
                    pd = fmaf(__uint_as_float(rw[i].w << 16),         vb.z, pd);
                    pd = fmaf(__uint_as_float(rw[i].w & 0xffff0000u), vb.w, pd);
#endif
                    pd += __shfl_xor(pd, 1);
                    pd += __shfl_xor(pd, 2);
                    pd += __shfl_xor(pd, 4);
                    pd += __shfl_xor(pd, 8);
                    float term = (recs[i] & 0x1000u)
                               ? (1.0f / NEGS) * log_sigmoid_fast(-pd)
                               : (1.0f / CTX)  * log_sigmoid_fast(pd);
                    if (t == 0 && ji < cnt) acc += term;
                }
            }
        }
    } else {
        // spill groups: f32 originals (exactness; expected ~0-2 entries)
        int sg = (lid - 2048) * 16 + grp;
        unsigned ns = *spillcnt; if (ns > SPILL_MAX) ns = SPILL_MAX;
        for (unsigned s = sg; s < ns; s += 16 * SPILL_BLOCKS) {
            unsigned e = spill[s];
            unsigned row = e >> 13, bb = (e >> 1) & 4095u;
            const char* rp = (const char*)W_os + ((row << 9) + ((unsigned)t << 5));
            float4 r0 = *(const float4*)rp, r1 = *(const float4*)(rp + 16);
            const char* vp2 = (const char*)ivec + ((bb << 9) + ((unsigned)t << 5));
            float4 v0 = *(const float4*)vp2, v1 = *(const float4*)(vp2 + 16);
            float pd = r0.x*v0.x + r0.y*v0.y + r0.z*v0.z + r0.w*v0.w
                     + r1.x*v1.x + r1.y*v1.y + r1.z*v1.z + r1.w*v1.w;
            pd += __shfl_xor(pd, 1);
            pd += __shfl_xor(pd, 2);
            pd += __shfl_xor(pd, 4);
            pd += __shfl_xor(pd, 8);
            float term = (e & 1u) ? (1.0f / NEGS) * log_sigmoid_fast(-pd)
                                  : (1.0f / CTX)  * log_sigmoid_fast(pd);
            if (t == 0) acc += term;
        }
    }

    acc += __shfl_xor(acc, 16);
    acc += __shfl_xor(acc, 32);
    __shared__ float wsum[4];
    if (lane == 0) wsum[wave] = acc;
    __syncthreads();
    if (threadIdx.x == 0) {
        float sum = wsum[0] + wsum[1] + wsum[2] + wsum[3];
        if (sum != 0.0f) atomicAdd(out, -sum);
    }
}

// ---- Kernel C (f32 rows, middle fallback) ----
__global__ __launch_bounds__(256) void bucket_loss_kernel(
    const float* __restrict__ W_os, const float* __restrict__ ivec,
    const unsigned short* __restrict__ records, const unsigned char* __restrict__ counts,
    const unsigned* __restrict__ spillcnt, const unsigned* __restrict__ spill,
    float* __restrict__ out)
{
    const int t    = threadIdx.x & 15;
    const int grp  = threadIdx.x >> 4;
    const int lane = threadIdx.x & 63;
    const int wave = threadIdx.x >> 6;
    const unsigned tb = (unsigned)t << 5;
    const unsigned* rec32 = (const unsigned*)records;

    float acc = 0.0f;
    const int lid = blockIdx.x;

    if (lid < 2048) {
        const int xcd = lid & 7;
        const int s   = lid >> 3;
        const unsigned bcell = (unsigned)(s * 16 + grp);

        const char* vp = (const char*)ivec + ((bcell << 9) + tb);
        const float4 v0 = *(const float4*)vp;
        const float4 v1 = *(const float4*)(vp + 16);

        for (int bk = 0; bk < NB / 8; ++bk) {
            const unsigned bucket = (unsigned)(xcd * (NB / 8) + bk);
            const unsigned cell   = (bucket << 12) + bcell;
            const unsigned cnt    = counts[cell];
            unsigned w = 0;
            if (t < 10) w = rec32[cell * 10u + (unsigned)t];

            for (unsigned base = 0; base < cnt; base += 8) {
                unsigned recs[8]; float4 r0[8], r1[8];
                #pragma unroll
                for (int i = 0; i < 8; ++i) {
                    unsigned ji = base + (unsigned)i;
                    int src = (grp << 4) + (int)(ji >> 1);
                    unsigned wv  = __shfl(w, src, 64);
                    unsigned rec = (i & 1) ? (wv >> 16) : (wv & 0xffffu);
                    recs[i] = rec;
                    unsigned rowg = (ji < cnt) ? (bucket * ROWS_PER_B + (rec & 0xfffu)) : 0u;
                    const char* rp = (const char*)W_os + ((rowg << 9) + tb);
                    r0[i] = *(const float4*)rp;
                    r1[i] = *(const float4*)(rp + 16);
                }
                #pragma unroll
                for (int i = 0; i < 8; ++i) {
                    unsigned ji = base + (unsigned)i;
                    float pd = r0[i].x*v0.x + r0[i].y*v0.y + r0[i].z*v0.z + r0[i].w*v0.w
                             + r1[i].x*v1.x + r1[i].y*v1.y + r1[i].z*v1.z + r1[i].w*v1.w;
                    pd += __shfl_xor(pd, 1);
                    pd += __shfl_xor(pd, 2);
                    pd += __shfl_xor(pd, 4);
                    pd += __shfl_xor(pd, 8);
                    float term = (recs[i] & 0x1000u)
                               ? (1.0f / NEGS) * log_sigmoid_fast(-pd)
                               : (1.0f / CTX)  * log_sigmoid_fast(pd);
                    if (t == 0 && ji < cnt) acc += term;
                }
            }
        }
    } else {
        int sg = (lid - 2048) * 16 + grp;
        unsigned ns = *spillcnt; if (ns > SPILL_MAX) ns = SPILL_MAX;
        for (unsigned s = sg; s < ns; s += 16 * SPILL_BLOCKS) {
            unsigned e = spill[s];
            unsigned row = e >> 13, bb = (e >> 1) & 4095u;
            const char* rp = (const char*)W_os + ((row << 9) + tb);
            float4 r0 = *(const float4*)rp, r1 = *(const float4*)(rp + 16);
            const char* vp2 = (const char*)ivec + ((bb << 9) + tb);
            float4 v0 = *(const float4*)vp2, v1 = *(const float4*)(vp2 + 16);
            float pd = r0.x*v0.x + r0.y*v0.y + r0.z*v0.z + r0.w*v0.w
                     + r1.x*v1.x + r1.y*v1.y + r1.z*v1.z + r1.w*v1.w;
            pd += __shfl_xor(pd, 1);
            pd += __shfl_xor(pd, 2);
            pd += __shfl_xor(pd, 4);
            pd += __shfl_xor(pd, 8);
            float term = (e & 1u) ? (1.0f / NEGS) * log_sigmoid_fast(-pd)
                                  : (1.0f / CTX)  * log_sigmoid_fast(pd);
            if (t == 0) acc += term;
        }
    }

    acc += __shfl_xor(acc, 16);
    acc += __shfl_xor(acc, 32);
    __shared__ float wsum[4];
    if (lane == 0) wsum[wave] = acc;
    __syncthreads();
    if (threadIdx.x == 0) {
        float sum = wsum[0] + wsum[1] + wsum[2] + wsum[3];
        if (sum != 0.0f) atomicAdd(out, -sum);
    }
}

// ---- Fallback (round-5 direct kernel) if ws too small ----
__global__ __launch_bounds__(256) void sgns_loss_direct(
    const int* __restrict__ i_words, const int* __restrict__ o_words,
    const int* __restrict__ n_words, const float* __restrict__ W_i,
    const float* __restrict__ W_os, float* __restrict__ out)
{
    const int lane = threadIdx.x & 63;
    const int wave = threadIdx.x >> 6;
    const int w    = blockIdx.x * 4 + wave;
    const int b    = w >> 1;
    const int h    = w & 1;
    const int sub = lane >> 4;
    const int t   = lane & 15;
    const int j_begin = h ? 112 : 0;
    const int j_end   = h ? NTARG : 112;
    float acc = 0.0f;
    const int ic = i_words[b];
    const char* ibase = (const char*)W_i + (((unsigned)ic << 9) + ((unsigned)t << 5));
    float4 i0 = *(const float4*)(ibase);
    float4 i1 = *(const float4*)(ibase + 16);
    #pragma unroll 4
    for (int j0 = j_begin; j0 < j_end; j0 += 4) {
        int jj = j0 + sub;
        int idx; float sgn, wgt;
        if (jj < CTX) { idx = o_words[jj * BATCH + b]; sgn = 1.0f; wgt = 1.0f / CTX; }
        else { idx = n_words[b * (CTX * NEGS) + (jj - CTX)]; sgn = -1.0f; wgt = 1.0f / NEGS; }
        const char* obase = (const char*)W_os + (((unsigned)idx << 9) + ((unsigned)t << 5));
        float4 o0 = *(const float4*)(obase);
        float4 o1 = *(const float4*)(obase + 16);
        float p = i0.x*o0.x + i0.y*o0.y + i0.z*o0.z + i0.w*o0.w
                + i1.x*o1.x + i1.y*o1.y + i1.z*o1.z + i1.w*o1.w;
        p += __shfl_xor(p, 1); p += __shfl_xor(p, 2);
        p += __shfl_xor(p, 4); p += __shfl_xor(p, 8);
        acc += (t == 0) ? wgt * log_sigmoid_fast(sgn * p) : 0.0f;
    }
    acc += __shfl_xor(acc, 16);
    acc += __shfl_xor(acc, 32);
    __shared__ float ws[4];
    if (lane == 0) ws[wave] = acc;
    __syncthreads();
    if (threadIdx.x == 0) atomicAdd(out, -(ws[0] + ws[1] + ws[2] + ws[3]));
}

extern "C" void kernel_launch(void* const* d_in, const int* in_sizes, int n_in,
                              void* d_out, int out_size, void* d_ws, size_t ws_size,
                              hipStream_t stream) {
    const int*   i_words = (const int*)d_in[0];
    const int*   o_words = (const int*)d_in[1];
    const int*   n_words = (const int*)d_in[2];
    const float* W_i     = (const float*)d_in[3];
    const float* W_os    = (const float*)d_in[4];
    float* out = (float*)d_out;

    hipMemsetAsync(out, 0, sizeof(float), stream);

    if (ws_size < (size_t)WS_NEEDED_MID) {
        sgns_loss_direct<<<2048, 256, 0, stream>>>(i_words, o_words, n_words, W_i, W_os, out);
        return;
    }

    char* ws = (char*)d_ws;
    unsigned char*  counts   = (unsigned char*)(ws + OFF_COUNTS);
    unsigned*       spillcnt = (unsigned*)(ws + OFF_SPILLCNT);
    unsigned*       spill    = (unsigned*)(ws + OFF_SPILL);
    unsigned short* records  = (unsigned short*)(ws + OFF_RECORDS);
    float*          ivec     = (float*)(ws + OFF_IVEC);
    unsigned short* wos16    = (unsigned short*)(ws + OFF_WOS16);

    hipMemsetAsync(spillcnt, 0, sizeof(unsigned), stream);

    if (ws_size >= (size_t)WS_NEEDED_BF16) {
        prep_kernel<<<768 + CONV_BLOCKS, 256, 0, stream>>>(
            i_words, o_words, n_words, (const float4*)W_i, (const float4*)W_os,
            (float4*)ivec, wos16, records, counts, spillcnt, spill);
        bucket_loss_bf16_kernel<<<2048 + SPILL_BLOCKS, 256, 0, stream>>>(
            wos16, W_os, ivec, records, counts, spillcnt, spill, out);
    } else {
        prep_kernel<<<768, 256, 0, stream>>>(
            i_words, o_words, n_words, (const float4*)W_i, (const float4*)W_os,
            (float4*)ivec, wos16, records, counts, spillcnt, spill);
        bucket_loss_kernel<<<2048 + SPILL_BLOCKS, 256, 0, stream>>>(
            W_os, ivec, records, counts, spillcnt, spill, out);
    }
}

// Round 14
// 69.596 us; speedup vs baseline: 1.0831x; 1.0388x over previous
//
#include <hip/hip_runtime.h>
#include <math.h>

#define VOCAB 100000
#define DIM 128
#define BATCH 4096
#define CTX 20
#define NEGS 10
#define NTARG (CTX + CTX * NEGS)   // 220
#define NB 32                      // row buckets: 3125 rows
#define ROWS_PER_B 3125
#define CAP 16                     // recs per (bucket,b) cell; lambda=6.875, P(>16)~8e-4
#define SPILL_MAX 8192
#define SPILL_BLOCKS 8

// d_ws layout (bytes) — tiered
#define OFF_COUNTS   0u            // u8[NB*BATCH] = 131072
#define OFF_SPILLCNT 131072u       // u32 (+pad to 131200)
#define OFF_SPILL    131200u       // u32[SPILL_MAX] = 32768
#define OFF_RECORDS  163968u       // u16[NB*BATCH*CAP] = 4194304
#define OFF_IVEC     4358272u      // f32[BATCH*DIM] = 2097152
#define WS_NEEDED_MID 6455424u
#define OFF_WOS16    6455424u      // bf16[VOCAB*DIM] = 25600000
#define WS_NEEDED_BF16 32055424u
#define CONV_BLOCKS 6250           // 12.8M floats / 8 per thread / 256

#if defined(__has_builtin)
#if __has_builtin(__builtin_amdgcn_fdot2_f32_bf16)
#define USE_DOT2 1
#endif
#endif

#ifdef USE_DOT2
typedef __bf16 bf16x2_t __attribute__((ext_vector_type(2)));
__device__ __forceinline__ bf16x2_t u2bf2(unsigned u) {
    union { unsigned u; bf16x2_t v; } c; c.u = u; return c.v;
}
#endif

__device__ __forceinline__ float log_sigmoid_fast(float x) {
    float a = fabsf(x);
    return fminf(x, 0.0f) - __logf(1.0f + __expf(-a));
}

__device__ __forceinline__ unsigned short f2bf_rtne(float f) {
    unsigned u = __float_as_uint(f);
    return (unsigned short)((u + 0x7fffu + ((u >> 16) & 1u)) >> 16);
}
__device__ __forceinline__ unsigned packbf2(float lo, float hi) {
    return ((unsigned)f2bf_rtne(hi) << 16) | f2bf_rtne(lo);
}

// dot of 16 bf16 pairs held as 2 uint4 vs 8 packed ivec words
__device__ __forceinline__ float dot16(uint4 a, uint4 b, const unsigned* iv) {
#ifdef USE_DOT2
    float pd;
    pd = __builtin_amdgcn_fdot2_f32_bf16(u2bf2(a.x), u2bf2(iv[0]), 0.0f, false);
    pd = __builtin_amdgcn_fdot2_f32_bf16(u2bf2(a.y), u2bf2(iv[1]), pd, false);
    pd = __builtin_amdgcn_fdot2_f32_bf16(u2bf2(a.z), u2bf2(iv[2]), pd, false);
    pd = __builtin_amdgcn_fdot2_f32_bf16(u2bf2(a.w), u2bf2(iv[3]), pd, false);
    pd = __builtin_amdgcn_fdot2_f32_bf16(u2bf2(b.x), u2bf2(iv[4]), pd, false);
    pd = __builtin_amdgcn_fdot2_f32_bf16(u2bf2(b.y), u2bf2(iv[5]), pd, false);
    pd = __builtin_amdgcn_fdot2_f32_bf16(u2bf2(b.z), u2bf2(iv[6]), pd, false);
    pd = __builtin_amdgcn_fdot2_f32_bf16(u2bf2(b.w), u2bf2(iv[7]), pd, false);
    return pd;
#else
    float pd = 0.0f;
    unsigned aw[8] = {a.x, a.y, a.z, a.w, b.x, b.y, b.z, b.w};
    #pragma unroll
    for (int k = 0; k < 8; ++k) {
        pd = fmaf(__uint_as_float(aw[k] << 16),         __uint_as_float(iv[k] << 16),         pd);
        pd = fmaf(__uint_as_float(aw[k] & 0xffff0000u), __uint_as_float(iv[k] & 0xffff0000u), pd);
    }
    return pd;
#endif
}

// ---- Kernel P: fused prep ----
// blocks [0,256):      scatter (16 ex/block, 16 thr/ex) -> LDS records -> coalesced writeout
// blocks [256,768):    ivec[b] = W_i[i_words[b]] f32 stage
// blocks [768,768+CONV_BLOCKS): W_os f32 -> bf16
__global__ __launch_bounds__(256) void prep_kernel(
    const int* __restrict__ i_words, const int* __restrict__ o_words,
    const int* __restrict__ n_words, const float4* __restrict__ W_i4,
    const float4* __restrict__ W_os4, float4* __restrict__ ivec4,
    unsigned short* __restrict__ wos16, unsigned short* __restrict__ records,
    unsigned char* __restrict__ counts, unsigned* __restrict__ spillcnt,
    unsigned* __restrict__ spill)
{
    if (blockIdx.x >= 768) {                     // W_os -> bf16, 8 floats/thread
        unsigned tid2 = (blockIdx.x - 768) * 256 + threadIdx.x;  // < 1.6M
        float4 a = W_os4[tid2 * 2];
        float4 b = W_os4[tid2 * 2 + 1];
        ushort4 lo, hi;
        lo.x = f2bf_rtne(a.x); lo.y = f2bf_rtne(a.y);
        lo.z = f2bf_rtne(a.z); lo.w = f2bf_rtne(a.w);
        hi.x = f2bf_rtne(b.x); hi.y = f2bf_rtne(b.y);
        hi.z = f2bf_rtne(b.z); hi.w = f2bf_rtne(b.w);
        ((ushort4*)wos16)[tid2 * 2]     = lo;
        ((ushort4*)wos16)[tid2 * 2 + 1] = hi;
        return;
    }
    if (blockIdx.x >= 256) {
        int tid = (blockIdx.x - 256) * 256 + threadIdx.x;   // 131072 = BATCH*32
        int b = tid >> 5, q = tid & 31;
        ivec4[tid] = W_i4[i_words[b] * 32 + q];
        return;
    }
    // scatter: 16 examples per block
    __shared__ unsigned       lcnt[NB * 16];          // 2 KB
    __shared__ unsigned short lrec[NB * 16 * CAP];    // 16 KB
    const int exl = threadIdx.x >> 4;
    const int tt  = threadIdx.x & 15;
    const int b   = blockIdx.x * 16 + exl;

    for (int k = threadIdx.x; k < NB * 16; k += 256) lcnt[k] = 0;
    __syncthreads();

    for (int j = tt; j < NTARG; j += 16) {
        int idx; unsigned negbit;
        if (j < CTX) { idx = o_words[j * BATCH + b];                negbit = 0u; }
        else         { idx = n_words[b * (CTX * NEGS) + (j - CTX)]; negbit = 0x1000u; }
        unsigned bucket = (unsigned)idx / ROWS_PER_B;
        unsigned rl     = (unsigned)idx - bucket * ROWS_PER_B;
        unsigned slot = atomicAdd(&lcnt[bucket * 16 + (unsigned)exl], 1u);
        if (slot < CAP) {
            lrec[(bucket * 16 + (unsigned)exl) * CAP + slot] = (unsigned short)(rl | negbit);
        } else {
            unsigned s = atomicAdd(spillcnt, 1u);
            if (s < SPILL_MAX) spill[s] = ((unsigned)idx << 13) | ((unsigned)b << 1) | (negbit ? 1u : 0u);
        }
    }
    __syncthreads();
    for (int k = threadIdx.x; k < NB * 16; k += 256) {
        unsigned c = lcnt[k];
        unsigned bucket = (unsigned)k >> 4, e2 = (unsigned)k & 15u;
        counts[(bucket << 12) + (unsigned)blockIdx.x * 16 + e2] = (unsigned char)(c < CAP ? c : CAP);
    }
    // coalesced records writeout: per bucket, 16 examples * 8 u32 = 512 B contiguous
    const unsigned* lrec32 = (const unsigned*)lrec;
    unsigned* grec32 = (unsigned*)records;
    for (int k = threadIdx.x; k < NB * 128; k += 256) {    // 4096 u32
        unsigned bucket = (unsigned)k >> 7;
        unsigned within = (unsigned)k & 127u;
        grec32[((bucket << 12) + (unsigned)blockIdx.x * 16u) * 8u + within] = lrec32[k];
    }
}

// ---- Kernel C (bf16 rows, 8-lane groups): one group per (bucket,b) cell ----
__global__ __launch_bounds__(256) void bucket_loss_bf16_kernel(
    const unsigned short* __restrict__ wos16, const float* __restrict__ W_os,
    const float* __restrict__ ivec,
    const unsigned short* __restrict__ records, const unsigned char* __restrict__ counts,
    const unsigned* __restrict__ spillcnt, const unsigned* __restrict__ spill,
    float* __restrict__ out)
{
    const int t    = threadIdx.x & 7;          // 8-lane groups
    const int grp  = threadIdx.x >> 3;         // 0..31 within block
    const int lane = threadIdx.x & 63;
    const int wave = threadIdx.x >> 6;
    const unsigned tb16 = (unsigned)t << 5;    // 32 B per lane in 256B bf16 row
    const unsigned* rec32 = (const unsigned*)records;

    float acc = 0.0f;
    const int lid = blockIdx.x;

    if (lid < 2048) {
        const int xcd  = lid & 7;
        const int s    = lid >> 3;             // 0..255
        const int half = s >> 7;               // 0/1: which pair of buckets
        const unsigned bcell = ((unsigned)(s & 127)) * 32u + (unsigned)grp;  // 0..4095

        // ivec slice: dims [t*16, t*16+16) as f32, packed once to 8 bf16x2 words
        const float4* vp = (const float4*)((const char*)ivec + ((bcell << 9) + ((unsigned)t << 6)));
        float4 va = vp[0], vb = vp[1], vc = vp[2], vd = vp[3];
        unsigned iv[8];
        iv[0] = packbf2(va.x, va.y); iv[1] = packbf2(va.z, va.w);
        iv[2] = packbf2(vb.x, vb.y); iv[3] = packbf2(vb.z, vb.w);
        iv[4] = packbf2(vc.x, vc.y); iv[5] = packbf2(vc.z, vc.w);
        iv[6] = packbf2(vd.x, vd.y); iv[7] = packbf2(vd.z, vd.w);

        for (int hb = 0; hb < 2; ++hb) {       // 2 buckets per group (XCD's half)
            const unsigned bucket = (unsigned)(xcd * 4 + half * 2 + hb);
            const unsigned cell   = (bucket << 12) + bcell;
            const unsigned cnt    = counts[cell];
            unsigned w = rec32[cell * 8u + (unsigned)t];   // 8 u32 recs, one per lane

            for (unsigned base = 0; base < cnt; base += 4) {
                unsigned recs[4]; uint4 rw0[4], rw1[4];
                #pragma unroll
                for (int i = 0; i < 4; ++i) {  // broadcast recs + 2 loads/pair
                    unsigned ji = base + (unsigned)i;
                    int src = (grp << 3) + (int)(ji >> 1);
                    unsigned wv  = __shfl(w, src, 64);
                    unsigned rec = (ji & 1u) ? (wv >> 16) : (wv & 0xffffu);
                    recs[i] = rec;
                    unsigned rowg = (ji < cnt) ? (bucket * ROWS_PER_B + (rec & 0xfffu)) : 0u;
                    const char* rp = (const char*)wos16 + ((rowg << 8) + tb16);
                    rw0[i] = *(const uint4*)rp;
                    rw1[i] = *(const uint4*)(rp + 16);
                }
                #pragma unroll
                for (int i = 0; i < 4; ++i) {  // dot + 3-step reduce + loss
                    unsigned ji = base + (unsigned)i;
                    float pd = dot16(rw0[i], rw1[i], iv);
                    pd += __shfl_xor(pd, 1);
                    pd += __shfl_xor(pd, 2);
                    pd += __shfl_xor(pd, 4);
                    float term = (recs[i] & 0x1000u)
                               ? (1.0f / NEGS) * log_sigmoid_fast(-pd)
                               : (1.0f / CTX)  * log_sigmoid_fast(pd);
                    if (t == 0 && ji < cnt) acc += term;
                }
            }
        }
    } else {
        // spill groups: f32 originals, 16-lane groups (exactness; ~100 entries)
        const int t16   = threadIdx.x & 15;
        const int grp16 = threadIdx.x >> 4;
        int sg = (lid - 2048) * 16 + grp16;
        unsigned ns = *spillcnt; if (ns > SPILL_MAX) ns = SPILL_MAX;
        for (unsigned s = sg; s < ns; s += 16 * SPILL_BLOCKS) {
            unsigned e = spill[s];
            unsigned row = e >> 13, bb = (e >> 1) & 4095u;
            const char* rp = (const char*)W_os + ((row << 9) + ((unsigned)t16 << 5));
            float4 r0 = *(const float4*)rp, r1 = *(const float4*)(rp + 16);
            const char* vp2 = (const char*)ivec + ((bb << 9) + ((unsigned)t16 << 5));
            float4 v0 = *(const float4*)vp2, v1 = *(const float4*)(vp2 + 16);
            float pd = r0.x*v0.x + r0.y*v0.y + r0.z*v0.z + r0.w*v0.w
                     + r1.x*v1.x + r1.y*v1.y + r1.z*v1.z + r1.w*v1.w;
            pd += __shfl_xor(pd, 1);
            pd += __shfl_xor(pd, 2);
            pd += __shfl_xor(pd, 4);
            pd += __shfl_xor(pd, 8);
            float term = (e & 1u) ? (1.0f / NEGS) * log_sigmoid_fast(-pd)
                                  : (1.0f / CTX)  * log_sigmoid_fast(pd);
            if (t16 == 0) acc += term;
        }
    }

    // acc nonzero on lanes ≡0 mod 8 (main) or mod 16 (spill)
    acc += __shfl_xor(acc, 8);
    acc += __shfl_xor(acc, 16);
    acc += __shfl_xor(acc, 32);
    __shared__ float wsum[4];
    if (lane == 0) wsum[wave] = acc;
    __syncthreads();
    if (threadIdx.x == 0) {
        float sum = wsum[0] + wsum[1] + wsum[2] + wsum[3];
        if (sum != 0.0f) atomicAdd(out, -sum);
    }
}

// ---- Kernel C (f32 rows, middle fallback; 16-lane groups, CAP=16 layout) ----
__global__ __launch_bounds__(256) void bucket_loss_kernel(
    const float* __restrict__ W_os, const float* __restrict__ ivec,
    const unsigned short* __restrict__ records, const unsigned char* __restrict__ counts,
    const unsigned* __restrict__ spillcnt, const unsigned* __restrict__ spill,
    float* __restrict__ out)
{
    const int t    = threadIdx.x & 15;
    const int grp  = threadIdx.x >> 4;
    const int lane = threadIdx.x & 63;
    const int wave = threadIdx.x >> 6;
    const unsigned tb = (unsigned)t << 5;
    const unsigned* rec32 = (const unsigned*)records;

    float acc = 0.0f;
    const int lid = blockIdx.x;

    if (lid < 2048) {
        const int xcd = lid & 7;
        const int s   = lid >> 3;
        const unsigned bcell = (unsigned)((s & 255) * 16 + grp);

        const char* vp = (const char*)ivec + ((bcell << 9) + tb);
        const float4 v0 = *(const float4*)vp;
        const float4 v1 = *(const float4*)(vp + 16);

        for (int bk = 0; bk < NB / 8; ++bk) {
            const unsigned bucket = (unsigned)(xcd * (NB / 8) + bk);
            const unsigned cell   = (bucket << 12) + bcell;
            const unsigned cnt    = counts[cell];
            unsigned w = 0;
            if (t < 8) w = rec32[cell * 8u + (unsigned)t];

            for (unsigned base = 0; base < cnt; base += 8) {
                unsigned recs[8]; float4 r0[8], r1[8];
                #pragma unroll
                for (int i = 0; i < 8; ++i) {
                    unsigned ji = base + (unsigned)i;
                    int src = (grp << 4) + (int)(ji >> 1);
                    unsigned wv  = __shfl(w, src, 64);
                    unsigned rec = (ji & 1u) ? (wv >> 16) : (wv & 0xffffu);
                    recs[i] = rec;
                    unsigned rowg = (ji < cnt) ? (bucket * ROWS_PER_B + (rec & 0xfffu)) : 0u;
                    const char* rp = (const char*)W_os + ((rowg << 9) + tb);
                    r0[i] = *(const float4*)rp;
                    r1[i] = *(const float4*)(rp + 16);
                }
                #pragma unroll
                for (int i = 0; i < 8; ++i) {
                    unsigned ji = base + (unsigned)i;
                    float pd = r0[i].x*v0.x + r0[i].y*v0.y + r0[i].z*v0.z + r0[i].w*v0.w
                             + r1[i].x*v1.x + r1[i].y*v1.y + r1[i].z*v1.z + r1[i].w*v1.w;
                    pd += __shfl_xor(pd, 1);
                    pd += __shfl_xor(pd, 2);
                    pd += __shfl_xor(pd, 4);
                    pd += __shfl_xor(pd, 8);
                    float term = (recs[i] & 0x1000u)
                               ? (1.0f / NEGS) * log_sigmoid_fast(-pd)
                               : (1.0f / CTX)  * log_sigmoid_fast(pd);
                    if (t == 0 && ji < cnt) acc += term;
                }
            }
        }
    } else {
        int sg = (lid - 2048) * 16 + grp;
        unsigned ns = *spillcnt; if (ns > SPILL_MAX) ns = SPILL_MAX;
        for (unsigned s = sg; s < ns; s += 16 * SPILL_BLOCKS) {
            unsigned e = spill[s];
            unsigned row = e >> 13, bb = (e >> 1) & 4095u;
            const char* rp = (const char*)W_os + ((row << 9) + tb);
            float4 r0 = *(const float4*)rp, r1 = *(const float4*)(rp + 16);
            const char* vp2 = (const char*)ivec + ((bb << 9) + tb);
            float4 v0 = *(const float4*)vp2, v1 = *(const float4*)(vp2 + 16);
            float pd = r0.x*v0.x + r0.y*v0.y + r0.z*v0.z + r0.w*v0.w
                     + r1.x*v1.x + r1.y*v1.y + r1.z*v1.z + r1.w*v1.w;
            pd += __shfl_xor(pd, 1);
            pd += __shfl_xor(pd, 2);
            pd += __shfl_xor(pd, 4);
            pd += __shfl_xor(pd, 8);
            float term = (e & 1u) ? (1.0f / NEGS) * log_sigmoid_fast(-pd)
                                  : (1.0f / CTX)  * log_sigmoid_fast(pd);
            if (t == 0) acc += term;
        }
    }

    acc += __shfl_xor(acc, 16);
    acc += __shfl_xor(acc, 32);
    __shared__ float wsum[4];
    if (lane == 0) wsum[wave] = acc;
    __syncthreads();
    if (threadIdx.x == 0) {
        float sum = wsum[0] + wsum[1] + wsum[2] + wsum[3];
        if (sum != 0.0f) atomicAdd(out, -sum);
    }
}

// ---- Fallback (round-5 direct kernel) if ws too small ----
__global__ __launch_bounds__(256) void sgns_loss_direct(
    const int* __restrict__ i_words, const int* __restrict__ o_words,
    const int* __restrict__ n_words, const float* __restrict__ W_i,
    const float* __restrict__ W_os, float* __restrict__ out)
{
    const int lane = threadIdx.x & 63;
    const int wave = threadIdx.x >> 6;
    const int w    = blockIdx.x * 4 + wave;
    const int b    = w >> 1;
    const int h    = w & 1;
    const int sub = lane >> 4;
    const int t   = lane & 15;
    const int j_begin = h ? 112 : 0;
    const int j_end   = h ? NTARG : 112;
    float acc = 0.0f;
    const int ic = i_words[b];
    const char* ibase = (const char*)W_i + (((unsigned)ic << 9) + ((unsigned)t << 5));
    float4 i0 = *(const float4*)(ibase);
    float4 i1 = *(const float4*)(ibase + 16);
    #pragma unroll 4
    for (int j0 = j_begin; j0 < j_end; j0 += 4) {
        int jj = j0 + sub;
        int idx; float sgn, wgt;
        if (jj < CTX) { idx = o_words[jj * BATCH + b]; sgn = 1.0f; wgt = 1.0f / CTX; }
        else { idx = n_words[b * (CTX * NEGS) + (jj - CTX)]; sgn = -1.0f; wgt = 1.0f / NEGS; }
        const char* obase = (const char*)W_os + (((unsigned)idx << 9) + ((unsigned)t << 5));
        float4 o0 = *(const float4*)(obase);
        float4 o1 = *(const float4*)(obase + 16);
        float p = i0.x*o0.x + i0.y*o0.y + i0.z*o0.z + i0.w*o0.w
                + i1.x*o1.x + i1.y*o1.y + i1.z*o1.z + i1.w*o1.w;
        p += __shfl_xor(p, 1); p += __shfl_xor(p, 2);
        p += __shfl_xor(p, 4); p += __shfl_xor(p, 8);
        acc += (t == 0) ? wgt * log_sigmoid_fast(sgn * p) : 0.0f;
    }
    acc += __shfl_xor(acc, 16);
    acc += __shfl_xor(acc, 32);
    __shared__ float ws[4];
    if (lane == 0) ws[wave] = acc;
    __syncthreads();
    if (threadIdx.x == 0) atomicAdd(out, -(ws[0] + ws[1] + ws[2] + ws[3]));
}

extern "C" void kernel_launch(void* const* d_in, const int* in_sizes, int n_in,
                              void* d_out, int out_size, void* d_ws, size_t ws_size,
                              hipStream_t stream) {
    const int*   i_words = (const int*)d_in[0];
    const int*   o_words = (const int*)d_in[1];
    const int*   n_words = (const int*)d_in[2];
    const float* W_i     = (const float*)d_in[3];
    const float* W_os    = (const float*)d_in[4];
    float* out = (float*)d_out;

    hipMemsetAsync(out, 0, sizeof(float), stream);

    if (ws_size < (size_t)WS_NEEDED_MID) {
        sgns_loss_direct<<<2048, 256, 0, stream>>>(i_words, o_words, n_words, W_i, W_os, out);
        return;
    }

    char* ws = (char*)d_ws;
    unsigned char*  counts   = (unsigned char*)(ws + OFF_COUNTS);
    unsigned*       spillcnt = (unsigned*)(ws + OFF_SPILLCNT);
    unsigned*       spill    = (unsigned*)(ws + OFF_SPILL);
    unsigned short* records  = (unsigned short*)(ws + OFF_RECORDS);
    float*          ivec     = (float*)(ws + OFF_IVEC);
    unsigned short* wos16    = (unsigned short*)(ws + OFF_WOS16);

    hipMemsetAsync(spillcnt, 0, sizeof(unsigned), stream);

    if (ws_size >= (size_t)WS_NEEDED_BF16) {
        prep_kernel<<<768 + CONV_BLOCKS, 256, 0, stream>>>(
            i_words, o_words, n_words, (const float4*)W_i, (const float4*)W_os,
            (float4*)ivec, wos16, records, counts, spillcnt, spill);
        bucket_loss_bf16_kernel<<<2048 + SPILL_BLOCKS, 256, 0, stream>>>(
            wos16, W_os, ivec, records, counts, spillcnt, spill, out);
    } else {
        prep_kernel<<<768, 256, 0, stream>>>(
            i_words, o_words, n_words, (const float4*)W_i, (const float4*)W_os,
            (float4*)ivec, wos16, records, counts, spillcnt, spill);
        bucket_loss_kernel<<<2048 + SPILL_BLOCKS, 256, 0, stream>>>(
            W_os, ivec, records, counts, spillcnt, spill, out);
    }
}